// Round 7
// baseline (301.872 us; speedup 1.0000x reference)
//
#include <hip/hip_runtime.h>
#include <math.h>

#define BB 8
#define CC 32
#define NTOK 241   // 4(q 2x2) + 121 + 64 + 36 + 16
#define NKV 237
#define YW 516

// ---------------------------------------------------------------------------
// Kernel A (v6): rotated-phase streaming pool. 1 block/plane (256 blocks).
// Block walks its plane's 512 rows in ROTATED order (start row = (plane*73)
// &511) so concurrent blocks' read fronts are de-phased across HBM channels.
// Thread owns 4 cols; 4 waves stride rows by 4; per-level window machines in
// registers emit raw H-sums into zeroed LDS via atomicAdd (wrap handled by
// mid-walk flush + re-init). Phase 2 W-pools LDS -> 241 tokens, plain stores.
// ---------------------------------------------------------------------------
template <int P, int NW, int SB>
struct WM {
  int idx, s, e;
  float ax, ay, az, aw;
  __device__ __forceinline__ void init(int row) {
    idx = (row * P) >> 9;                    // first window with e > row
    s = (idx * 512) / P;
    e = ((idx + 1) * 512 + P - 1) / P;
    ax = ay = az = aw = 0.f;
  }
  __device__ __forceinline__ void flush(float* __restrict__ Y, int c4) {
    if (idx < NW) {
      float* dst = Y + (SB + idx) * YW + c4;
      atomicAdd(dst + 0, ax);
      atomicAdd(dst + 1, ay);
      atomicAdd(dst + 2, az);
      atomicAdd(dst + 3, aw);
    }
  }
  __device__ __forceinline__ void step(float4 v, int r, float* __restrict__ Y,
                                       int c4) {
    if (r >= s && r < e) { ax += v.x; ay += v.y; az += v.z; aw += v.w; }
    if (r < e && r + 4 >= e) {               // last visited row of window
      flush(Y, c4);
      idx++;
      int sn = (idx * 512) / P;
      e = ((idx + 1) * 512 + P - 1) / P;
      bool ov = (sn <= r) && (idx < NW);     // adjacent windows overlap <=1 row
      ax = ov ? v.x : 0.f; ay = ov ? v.y : 0.f;
      az = ov ? v.z : 0.f; aw = ov ? v.w : 0.f;
      s = sn;
    }
  }
};

__global__ __launch_bounds__(512) void pool_kernel(const float* __restrict__ x,
                                                   float* __restrict__ pooled) {
  __shared__ float Ybuf[31 * YW];            // 63,984 B (raw H-sums)

  const int plane = blockIdx.x;              // b*32 + c
  const int tid = threadIdx.x;
  const int r0 = tid >> 7;                   // 0..3 (wave-pair granular)
  const int c4 = (tid & 127) * 4;
  const float* xp = x + (size_t)plane * (512 * 512);

  for (int i = tid; i < 31 * YW; i += 512) Ybuf[i] = 0.f;

  const int off = (plane * 73) & 511;        // per-plane phase rotation
  int i_w = (512 - off - r0 + 3) >> 2;       // wrap iteration (0..128)
  if (i_w > 128) i_w = 128;
  const int row0 = (off + r0) & 511;

  WM<2, 2, 0> M2;    M2.init(row0);
  WM<11, 11, 2> M11; M11.init(row0);
  WM<8, 8, 13> M8;   M8.init(row0);
  WM<6, 6, 21> M6;   M6.init(row0);
  WM<4, 4, 27> M4;   M4.init(row0);

  __syncthreads();                           // Ybuf zeroed

#define ROWOF(IT) ((off + r0 + 4 * (IT)) & 511)
#define LOADIT(IT) (*(const float4*)(xp + (size_t)ROWOF(IT) * 512 + c4))
#define FLUSHALL                                                               \
  { M2.flush(Ybuf, c4); M11.flush(Ybuf, c4); M8.flush(Ybuf, c4);               \
    M6.flush(Ybuf, c4); M4.flush(Ybuf, c4); }
#define REINIT(ROW)                                                            \
  { M2.init(ROW); M11.init(ROW); M8.init(ROW); M6.init(ROW); M4.init(ROW); }
#define PROCIT(V, IT)                                                          \
  {                                                                            \
    if ((IT) == i_w) { FLUSHALL; REINIT(ROWOF(IT)); }                          \
    int r = ROWOF(IT);                                                         \
    M2.step(V, r, Ybuf, c4);                                                   \
    M11.step(V, r, Ybuf, c4);                                                  \
    M8.step(V, r, Ybuf, c4);                                                   \
    M6.step(V, r, Ybuf, c4);                                                   \
    M4.step(V, r, Ybuf, c4);                                                   \
  }

  float4 Av = LOADIT(0), Bv = LOADIT(1), Cv = LOADIT(2), Dv = LOADIT(3);
  for (int it = 0; it < 128; it += 4) {
    PROCIT(Av, it);     Av = LOADIT(it + 4);
    PROCIT(Bv, it + 1); Bv = LOADIT(it + 5);
    PROCIT(Cv, it + 2); Cv = LOADIT(it + 6);
    PROCIT(Dv, it + 3); Dv = LOADIT(it + 7);
  }
  FLUSHALL;                                  // tail partial (idx-guarded)
#undef ROWOF
#undef LOADIT
#undef FLUSHALL
#undef REINIT
#undef PROCIT
  __syncthreads();

  // Phase 2: W-pool the 31x512 raw-sum intermediate into 241 tokens.
  if (tid < NTOK) {
    int k = tid, p, sbase, kb;
    if (k < 4)        { p = 2;  sbase = 0;  kb = 0; }
    else if (k < 125) { p = 11; sbase = 2;  kb = 4; }
    else if (k < 189) { p = 8;  sbase = 13; kb = 125; }
    else if (k < 225) { p = 6;  sbase = 21; kb = 189; }
    else              { p = 4;  sbase = 27; kb = 225; }
    int idx = k - kb, i = idx / p, j = idx - i * p;
    int si = (i * 512) / p, ei = ((i + 1) * 512 + p - 1) / p;
    int sw = (j * 512) / p, ew = ((j + 1) * 512 + p - 1) / p;
    const float* row = &Ybuf[(sbase + i) * YW];
    float t0 = 0.f, t1 = 0.f, t2 = 0.f, t3 = 0.f;
    int cc = sw;
    for (; cc + 4 <= ew; cc += 4) {
      t0 += row[cc]; t1 += row[cc + 1]; t2 += row[cc + 2]; t3 += row[cc + 3];
    }
    for (; cc < ew; ++cc) t0 += row[cc];
    float val = ((t0 + t1) + (t2 + t3)) / (float)((ei - si) * (ew - sw));
    pooled[(size_t)plane * NTOK + k] = val;
  }
}

// ---------------------------------------------------------------------------
// Kernel B: token pipeline (dw-conv residual, LN, q/kv linears, attention,
// proj). One block per batch element. (unchanged, validated)
// ---------------------------------------------------------------------------
__global__ __launch_bounds__(512) void attn_kernel(
    const float* __restrict__ pooled,
    const float* __restrict__ q_w, const float* __restrict__ q_b,
    const float* __restrict__ kv_w, const float* __restrict__ kv_b,
    const float* __restrict__ proj_w, const float* __restrict__ proj_b,
    const float* __restrict__ norm_g, const float* __restrict__ norm_b,
    const float* __restrict__ dconv_w, const float* __restrict__ dconv_b,
    float* __restrict__ o_out) {
  __shared__ float pl[CC * NTOK];
  __shared__ float toks[NKV][33];
  __shared__ float kvls[NKV][65];      // k: 0..31, v: 32..63
  __shared__ float kvw[CC * 64];
  __shared__ float dw[4 * CC * 9];
  __shared__ float dbias[4 * CC];
  __shared__ float qbias[CC], kvb[64], gln[CC], bln[CC];
  __shared__ float qtok[4][CC];
  __shared__ float attno[4][33];

  const int b = blockIdx.x, tid = threadIdx.x;
  const float* plg = pooled + (size_t)b * CC * NTOK;
  for (int i = tid; i < CC * NTOK; i += 512) pl[i] = plg[i];
  for (int i = tid; i < CC * 64; i += 512) kvw[i] = kv_w[i];
  for (int i = tid; i < 4 * CC * 9; i += 512) dw[i] = dconv_w[i];
  if (tid < 4 * CC) dbias[tid] = dconv_b[tid];
  if (tid < CC) { qbias[tid] = q_b[tid]; gln[tid] = norm_g[tid]; bln[tid] = norm_b[tid]; }
  if (tid >= 64 && tid < 128) kvb[tid - 64] = kv_b[tid - 64];
  __syncthreads();

  // depthwise 3x3 conv (SAME, zero pad) + residual -> toks
  for (int item = tid; item < NKV * CC; item += 512) {
    int t = item >> 5, c = item & 31;
    int l, p, kb_, tb;
    if (t < 121)      { l = 0; p = 11; kb_ = 4;   tb = 0; }
    else if (t < 185) { l = 1; p = 8;  kb_ = 125; tb = 121; }
    else if (t < 221) { l = 2; p = 6;  kb_ = 189; tb = 185; }
    else              { l = 3; p = 4;  kb_ = 225; tb = 221; }
    int ti = t - tb;
    int i = ti / p, j = ti - i * p;
    const float* plc = pl + c * NTOK + kb_;
    const float* w9 = dw + (l * CC + c) * 9;
    float acc = dbias[l * CC + c];
#pragma unroll
    for (int dy = -1; dy <= 1; ++dy)
#pragma unroll
      for (int dx = -1; dx <= 1; ++dx) {
        int ii = i + dy, jj = j + dx;
        if (ii >= 0 && ii < p && jj >= 0 && jj < p)
          acc += w9[(dy + 1) * 3 + (dx + 1)] * plc[ii * p + jj];
      }
    toks[t][c] = plc[i * p + j] + acc;
  }
  __syncthreads();

  // LayerNorm over C (threads 0..236) ; q linear (threads 384..511)
  if (tid < NKV) {
    float xv[32]; float m = 0.f;
#pragma unroll
    for (int c = 0; c < 32; ++c) { xv[c] = toks[tid][c]; m += xv[c]; }
    m *= (1.0f / 32.0f);
    float v = 0.f;
#pragma unroll
    for (int c = 0; c < 32; ++c) { float d = xv[c] - m; v += d * d; }
    v *= (1.0f / 32.0f);
    float rs = rsqrtf(v + 1e-5f);
#pragma unroll
    for (int c = 0; c < 32; ++c) toks[tid][c] = (xv[c] - m) * rs * gln[c] + bln[c];
  } else if (tid >= 384) {
    int it = tid - 384;
    int n = it >> 5, u = it & 31;
    float acc = qbias[u];
#pragma unroll
    for (int c = 0; c < 32; ++c) acc += pl[c * NTOK + n] * q_w[c * 32 + u];
    qtok[n][u] = acc * 0.25f;         // fold scale = hd^-0.5
  }
  __syncthreads();

  // kv = toks_ln @ kv_w + kv_b   (237 x 64)
  for (int item = tid; item < NKV * 64; item += 512) {
    int t = item >> 6, u = item & 63;
    float acc = kvb[u];
#pragma unroll
    for (int c = 0; c < 32; ++c) acc += toks[t][c] * kvw[c * 64 + u];
    kvls[t][u] = acc;
  }
  __syncthreads();

  // attention: 8 waves <-> 8 (head, query) pairs
  {
    int wave = tid >> 6, lane = tid & 63;
    int h = wave >> 2, qi = wave & 3;
    float qv[16];
#pragma unroll
    for (int d = 0; d < 16; ++d) qv[d] = qtok[qi][h * 16 + d];
    float sc[4];
#pragma unroll
    for (int m = 0; m < 4; ++m) {
      int t = lane + m * 64;
      float s = -1e30f;
      if (t < NKV) {
        s = 0.f;
#pragma unroll
        for (int d = 0; d < 16; ++d) s += qv[d] * kvls[t][h * 16 + d];
      }
      sc[m] = s;
    }
    float mx = fmaxf(fmaxf(sc[0], sc[1]), fmaxf(sc[2], sc[3]));
#pragma unroll
    for (int d = 1; d < 64; d <<= 1) mx = fmaxf(mx, __shfl_xor(mx, d));
    float pr[4]; float ssum = 0.f;
#pragma unroll
    for (int m = 0; m < 4; ++m) {
      int t = lane + m * 64;
      pr[m] = (t < NKV) ? expf(sc[m] - mx) : 0.0f;
      ssum += pr[m];
    }
#pragma unroll
    for (int d = 1; d < 64; d <<= 1) ssum += __shfl_xor(ssum, d);
    float acc[16];
#pragma unroll
    for (int d = 0; d < 16; ++d) acc[d] = 0.f;
#pragma unroll
    for (int m = 0; m < 4; ++m) {
      int t = lane + m * 64;
      if (t < NKV) {
        float p = pr[m];
#pragma unroll
        for (int d = 0; d < 16; ++d) acc[d] += p * kvls[t][32 + h * 16 + d];
      }
    }
#pragma unroll
    for (int d = 0; d < 16; ++d) {
#pragma unroll
      for (int s = 1; s < 64; s <<= 1) acc[d] += __shfl_xor(acc[d], s);
    }
    if (lane == 0) {
      float inv = 1.0f / ssum;
#pragma unroll
      for (int d = 0; d < 16; ++d) attno[qi][h * 16 + d] = acc[d] * inv;
    }
  }
  __syncthreads();

  // proj: (4 x 32) @ proj_w + proj_b -> o_out[(b*32+u)*4 + n]
  if (tid < 128) {
    int n = tid >> 5, u = tid & 31;
    float acc = proj_b[u];
#pragma unroll
    for (int c = 0; c < 32; ++c) acc += attno[n][c] * proj_w[c * 32 + u];
    o_out[((size_t)b * 32 + u) * 4 + n] = acc;
  }
}

// ---------------------------------------------------------------------------
// Kernel C (v2): bilinear upsample, GLOBAL row-interleave (fill-like front).
// wave w handles global rows w, w+4096, ... ; one row = 2 KB contiguous.
// ---------------------------------------------------------------------------
__global__ __launch_bounds__(256) void upsample_kernel(const float* __restrict__ o_in,
                                                       float* __restrict__ out) {
  const int tid = threadIdx.x;
  const int wv = tid >> 6, lane = tid & 63;
  const int gw0 = blockIdx.x * 4 + wv;

  float ww[8];
#pragma unroll
  for (int k = 0; k < 8; ++k) {
    float cx = (float)(lane * 8 + k) + 0.5f;
    float w = cx * (1.0f / 256.0f) - 0.5f;
    ww[k] = fminf(fmaxf(w, 0.0f), 1.0f);
  }

  for (int g = gw0; g < 256 * 512; g += 4096) {
    int plane = g >> 9, r = g & 511;
    float o00 = o_in[plane * 4 + 0];
    float o01 = o_in[plane * 4 + 1];
    float o10 = o_in[plane * 4 + 2];
    float o11 = o_in[plane * 4 + 3];
    float wh = ((float)r + 0.5f) * (1.0f / 256.0f) - 0.5f;
    wh = fminf(fmaxf(wh, 0.0f), 1.0f);
    float v[8];
#pragma unroll
    for (int k = 0; k < 8; ++k) {
      float t = o00 + ww[k] * (o01 - o00);
      float bb = o10 + ww[k] * (o11 - o10);
      v[k] = t + wh * (bb - t);
    }
    float* op = out + (size_t)g * 512 + lane * 8;
    *(float4*)op = make_float4(v[0], v[1], v[2], v[3]);
    *(float4*)(op + 4) = make_float4(v[4], v[5], v[6], v[7]);
  }
}

extern "C" void kernel_launch(void* const* d_in, const int* in_sizes, int n_in,
                              void* d_out, int out_size, void* d_ws, size_t ws_size,
                              hipStream_t stream) {
  const float* x       = (const float*)d_in[0];
  const float* q_w     = (const float*)d_in[1];
  const float* q_b     = (const float*)d_in[2];
  const float* kv_w    = (const float*)d_in[3];
  const float* kv_b    = (const float*)d_in[4];
  const float* proj_w  = (const float*)d_in[5];
  const float* proj_b  = (const float*)d_in[6];
  const float* norm_g  = (const float*)d_in[7];
  const float* norm_b  = (const float*)d_in[8];
  const float* dconv_w = (const float*)d_in[9];
  const float* dconv_b = (const float*)d_in[10];
  float* out = (float*)d_out;

  float* pooled = (float*)d_ws;                     // 256*241 floats
  float* o_ws   = pooled + (size_t)BB * CC * NTOK;  // 1024 floats

  pool_kernel<<<BB * CC, 512, 0, stream>>>(x, pooled);
  attn_kernel<<<BB, 512, 0, stream>>>(pooled, q_w, q_b, kv_w, kv_b, proj_w,
                                      proj_b, norm_g, norm_b, dconv_w, dconv_b,
                                      o_ws);
  upsample_kernel<<<1024, 256, 0, stream>>>(o_ws, out);
}

// Round 8
// 216.934 us; speedup vs baseline: 1.3915x; 1.3915x over previous
//
#include <hip/hip_runtime.h>
#include <math.h>

#define BB 8
#define CC 32
#define NTOK 241   // 4(q 2x2) + 121 + 64 + 36 + 16
#define NKV 237

// ---------------------------------------------------------------------------
// Pool stage A (fill-shaped): 256 planes x 64 bands(8 rows) = 16384 blocks,
// 256 thr. Thread sums 4 rows of one col-quad -> one float4 store into G4
// [plane][128 groups][512]. 4 loads + 3 adds + 1 store, no loops/barriers.
// ---------------------------------------------------------------------------
__global__ __launch_bounds__(256) void g4_kernel(const float* __restrict__ x,
                                                 float* __restrict__ G4) {
  const int b = blockIdx.x;
  const int plane = b >> 6, band = b & 63;
  const int t = threadIdx.x;
  const int gh = t >> 7;                     // which 4-row group of the band
  const int c4 = (t & 127) * 4;
  const float* xp = x + (size_t)plane * (512 * 512) + (size_t)(band * 8 + gh * 4) * 512 + c4;
  float4 a0 = *(const float4*)(xp);
  float4 a1 = *(const float4*)(xp + 512);
  float4 a2 = *(const float4*)(xp + 1024);
  float4 a3 = *(const float4*)(xp + 1536);
  float4 s;
  s.x = (a0.x + a1.x) + (a2.x + a3.x);
  s.y = (a0.y + a1.y) + (a2.y + a3.y);
  s.z = (a0.z + a1.z) + (a2.z + a3.z);
  s.w = (a0.w + a1.w) + (a2.w + a3.w);
  *(float4*)(G4 + ((size_t)plane * 128 + band * 2 + gh) * 512 + c4) = s;
}

// ---------------------------------------------------------------------------
// Pool stage B: 256 planes x 5 levels = 1280 blocks, 512 thr. Assemble each
// H-window from G4 group sums + raw x edge rows (p11/p6 only), W-pool in LDS
// -> tokens. No atomics, each token written exactly once.
// ---------------------------------------------------------------------------
__global__ __launch_bounds__(512) void win_kernel(const float* __restrict__ x,
                                                  const float* __restrict__ G4,
                                                  float* __restrict__ pooled) {
  __shared__ float Y[11][520];               // 22.9 KB
  const int b = blockIdx.x;
  const int plane = b / 5, lvl = b - plane * 5;
  const int Ps[5]  = {2, 11, 8, 6, 4};
  const int KBs[5] = {0, 4, 125, 189, 225};
  const int p = Ps[lvl], kb = KBs[lvl];
  const int col = threadIdx.x;
  const float* xp = x + (size_t)plane * (512 * 512);
  const float* g4 = G4 + (size_t)plane * 128 * 512;

  for (int i = 0; i < p; ++i) {
    int s = (i * 512) / p, e = ((i + 1) * 512 + p - 1) / p;
    int gs = (s + 3) >> 2, ge = e >> 2;
    float sum = 0.f;
    for (int r = s; r < gs * 4; ++r) sum += xp[(size_t)r * 512 + col];
    float s0 = 0.f, s1 = 0.f;
    int g = gs;
    for (; g + 2 <= ge; g += 2) {
      s0 += g4[(size_t)g * 512 + col];
      s1 += g4[(size_t)(g + 1) * 512 + col];
    }
    if (g < ge) s0 += g4[(size_t)g * 512 + col];
    sum += s0 + s1;
    for (int r = ge * 4; r < e; ++r) sum += xp[(size_t)r * 512 + col];
    Y[i][col] = sum;
  }
  __syncthreads();

  if (col < p * p) {
    int i = col / p, j = col - i * p;
    int s = (i * 512) / p, e = ((i + 1) * 512 + p - 1) / p;
    int sw = (j * 512) / p, ew = ((j + 1) * 512 + p - 1) / p;
    float t0 = 0.f, t1 = 0.f;
    int c = sw;
    for (; c + 2 <= ew; c += 2) { t0 += Y[i][c]; t1 += Y[i][c + 1]; }
    if (c < ew) t0 += Y[i][c];
    pooled[(size_t)plane * NTOK + kb + i * p + j] =
        (t0 + t1) / (float)((e - s) * (ew - sw));
  }
}

// ---------------------------------------------------------------------------
// Fallback pool (validated R5 band kernel) if ws_size can't hold G4.
// ---------------------------------------------------------------------------
struct Win { int idx, s, e, left; float acc; };

template <int P, int SBASE>
__device__ __forceinline__ void wstep(Win& w, int nown, float v, int r,
                                      float* __restrict__ Y, int c) {
  if (w.left > 0) {
    w.acc += (r >= w.s) ? v : 0.0f;
    if (r == w.e - 1) {
      Y[(SBASE + (nown - w.left)) * 516 + c] = w.acc;
      w.left--; w.idx++;
      int sn = (w.idx * 512) / P;
      w.acc = (sn <= r) ? v : 0.0f;
      w.s = sn;
      w.e = ((w.idx + 1) * 512 + P - 1) / P;
    }
  }
}

template <int P>
__device__ __forceinline__ void winit(Win& w, int i0, int n) {
  w.idx = i0;
  w.s = (i0 * 512) / P;
  w.e = ((i0 + 1) * 512 + P - 1) / P;
  w.left = n;
  w.acc = 0.0f;
}

__global__ __launch_bounds__(512) void pool_fb(const float* __restrict__ x,
                                               float* __restrict__ pooled) {
  __shared__ float sh[8 * 512];
  __shared__ float Ybuf[16 * 516];
  const int plane = blockIdx.x >> 1;
  const int q = blockIdx.x & 1;
  const int tid = threadIdx.x;
  const int c = tid;
  const int lo = q ? 256 : 0;
  const int nb = q ? 32 : 35;
  int i0_2, n_2, i0_11, n_11, i0_8, n_8, i0_6, n_6, i0_4, n_4;
  if (q == 0) { i0_2 = 0; n_2 = 1; i0_11 = 0; n_11 = 6; i0_8 = 0; n_8 = 4; i0_6 = 0; n_6 = 3; i0_4 = 0; n_4 = 2; }
  else        { i0_2 = 1; n_2 = 1; i0_11 = 6; n_11 = 5; i0_8 = 4; n_8 = 4; i0_6 = 3; n_6 = 3; i0_4 = 2; n_4 = 2; }
  Win W2, W11, W8, W6, W4;
  winit<2>(W2, i0_2, n_2); winit<11>(W11, i0_11, n_11); winit<8>(W8, i0_8, n_8);
  winit<6>(W6, i0_6, n_6); winit<4>(W4, i0_4, n_4);
  const float* xp = x + (size_t)plane * (512 * 512);
  const int row0 = tid >> 7;
  const int cg = (tid & 127) * 4;
  float4 r0 = *(const float4*)(xp + (size_t)(lo + row0) * 512 + cg);
  float4 r1 = *(const float4*)(xp + (size_t)(lo + row0 + 4) * 512 + cg);
  for (int band = 0; band < nb; ++band) {
    *(float4*)(sh + row0 * 512 + cg) = r0;
    *(float4*)(sh + (row0 + 4) * 512 + cg) = r1;
    __syncthreads();
    if (band + 1 < nb) {
      int rb = lo + (band + 1) * 8;
      r0 = *(const float4*)(xp + (size_t)(rb + row0) * 512 + cg);
      r1 = *(const float4*)(xp + (size_t)(rb + row0 + 4) * 512 + cg);
    }
#pragma unroll
    for (int rr = 0; rr < 8; ++rr) {
      float v = sh[rr * 512 + c];
      int r = lo + band * 8 + rr;
      wstep<2, 0>(W2, n_2, v, r, Ybuf, c);
      wstep<11, 1>(W11, n_11, v, r, Ybuf, c);
      wstep<8, 7>(W8, n_8, v, r, Ybuf, c);
      wstep<6, 11>(W6, n_6, v, r, Ybuf, c);
      wstep<4, 14>(W4, n_4, v, r, Ybuf, c);
    }
    __syncthreads();
  }
  const int Ps[5]  = {2, 11, 8, 6, 4};
  const int KBs[5] = {0, 4, 125, 189, 225};
  const int SBs[5] = {0, 1, 7, 11, 14};
  const int i0s[5] = {i0_2, i0_11, i0_8, i0_6, i0_4};
  const int ns[5]  = {n_2, n_11, n_8, n_6, n_4};
  int cum[6]; cum[0] = 0;
#pragma unroll
  for (int l = 0; l < 5; ++l) cum[l + 1] = cum[l] + ns[l] * Ps[l];
  if (tid < cum[5]) {
    int l = 0;
    while (tid >= cum[l + 1]) ++l;
    int P = Ps[l];
    int rel = tid - cum[l];
    int li = rel / P, j = rel - li * P;
    int i = i0s[l] + li;
    int s = (i * 512) / P, e = ((i + 1) * 512 + P - 1) / P;
    int sw = (j * 512) / P, ew = ((j + 1) * 512 + P - 1) / P;
    const float* row = &Ybuf[(SBs[l] + li) * 516];
    float t0 = 0.f, t1 = 0.f, t2 = 0.f, t3 = 0.f;
    int cc = sw;
    for (; cc + 4 <= ew; cc += 4) {
      t0 += row[cc]; t1 += row[cc + 1]; t2 += row[cc + 2]; t3 += row[cc + 3];
    }
    for (; cc < ew; ++cc) t0 += row[cc];
    float val = ((t0 + t1) + (t2 + t3)) / (float)((e - s) * (ew - sw));
    pooled[(size_t)plane * NTOK + KBs[l] + i * P + j] = val;
  }
}

// ---------------------------------------------------------------------------
// Kernel B: token pipeline (unchanged, validated).
// ---------------------------------------------------------------------------
__global__ __launch_bounds__(512) void attn_kernel(
    const float* __restrict__ pooled,
    const float* __restrict__ q_w, const float* __restrict__ q_b,
    const float* __restrict__ kv_w, const float* __restrict__ kv_b,
    const float* __restrict__ proj_w, const float* __restrict__ proj_b,
    const float* __restrict__ norm_g, const float* __restrict__ norm_b,
    const float* __restrict__ dconv_w, const float* __restrict__ dconv_b,
    float* __restrict__ o_out) {
  __shared__ float pl[CC * NTOK];
  __shared__ float toks[NKV][33];
  __shared__ float kvls[NKV][65];      // k: 0..31, v: 32..63
  __shared__ float kvw[CC * 64];
  __shared__ float dw[4 * CC * 9];
  __shared__ float dbias[4 * CC];
  __shared__ float qbias[CC], kvb[64], gln[CC], bln[CC];
  __shared__ float qtok[4][CC];
  __shared__ float attno[4][33];

  const int b = blockIdx.x, tid = threadIdx.x;
  const float* plg = pooled + (size_t)b * CC * NTOK;
  for (int i = tid; i < CC * NTOK; i += 512) pl[i] = plg[i];
  for (int i = tid; i < CC * 64; i += 512) kvw[i] = kv_w[i];
  for (int i = tid; i < 4 * CC * 9; i += 512) dw[i] = dconv_w[i];
  if (tid < 4 * CC) dbias[tid] = dconv_b[tid];
  if (tid < CC) { qbias[tid] = q_b[tid]; gln[tid] = norm_g[tid]; bln[tid] = norm_b[tid]; }
  if (tid >= 64 && tid < 128) kvb[tid - 64] = kv_b[tid - 64];
  __syncthreads();

  for (int item = tid; item < NKV * CC; item += 512) {
    int t = item >> 5, c = item & 31;
    int l, p, kb_, tb;
    if (t < 121)      { l = 0; p = 11; kb_ = 4;   tb = 0; }
    else if (t < 185) { l = 1; p = 8;  kb_ = 125; tb = 121; }
    else if (t < 221) { l = 2; p = 6;  kb_ = 189; tb = 185; }
    else              { l = 3; p = 4;  kb_ = 225; tb = 221; }
    int ti = t - tb;
    int i = ti / p, j = ti - i * p;
    const float* plc = pl + c * NTOK + kb_;
    const float* w9 = dw + (l * CC + c) * 9;
    float acc = dbias[l * CC + c];
#pragma unroll
    for (int dy = -1; dy <= 1; ++dy)
#pragma unroll
      for (int dx = -1; dx <= 1; ++dx) {
        int ii = i + dy, jj = j + dx;
        if (ii >= 0 && ii < p && jj >= 0 && jj < p)
          acc += w9[(dy + 1) * 3 + (dx + 1)] * plc[ii * p + jj];
      }
    toks[t][c] = plc[i * p + j] + acc;
  }
  __syncthreads();

  if (tid < NKV) {
    float xv[32]; float m = 0.f;
#pragma unroll
    for (int c = 0; c < 32; ++c) { xv[c] = toks[tid][c]; m += xv[c]; }
    m *= (1.0f / 32.0f);
    float v = 0.f;
#pragma unroll
    for (int c = 0; c < 32; ++c) { float d = xv[c] - m; v += d * d; }
    v *= (1.0f / 32.0f);
    float rs = rsqrtf(v + 1e-5f);
#pragma unroll
    for (int c = 0; c < 32; ++c) toks[tid][c] = (xv[c] - m) * rs * gln[c] + bln[c];
  } else if (tid >= 384) {
    int it = tid - 384;
    int n = it >> 5, u = it & 31;
    float acc = qbias[u];
#pragma unroll
    for (int c = 0; c < 32; ++c) acc += pl[c * NTOK + n] * q_w[c * 32 + u];
    qtok[n][u] = acc * 0.25f;         // fold scale = hd^-0.5
  }
  __syncthreads();

  for (int item = tid; item < NKV * 64; item += 512) {
    int t = item >> 6, u = item & 63;
    float acc = kvb[u];
#pragma unroll
    for (int c = 0; c < 32; ++c) acc += toks[t][c] * kvw[c * 64 + u];
    kvls[t][u] = acc;
  }
  __syncthreads();

  {
    int wave = tid >> 6, lane = tid & 63;
    int h = wave >> 2, qi = wave & 3;
    float qv[16];
#pragma unroll
    for (int d = 0; d < 16; ++d) qv[d] = qtok[qi][h * 16 + d];
    float sc[4];
#pragma unroll
    for (int m = 0; m < 4; ++m) {
      int t = lane + m * 64;
      float s = -1e30f;
      if (t < NKV) {
        s = 0.f;
#pragma unroll
        for (int d = 0; d < 16; ++d) s += qv[d] * kvls[t][h * 16 + d];
      }
      sc[m] = s;
    }
    float mx = fmaxf(fmaxf(sc[0], sc[1]), fmaxf(sc[2], sc[3]));
#pragma unroll
    for (int d = 1; d < 64; d <<= 1) mx = fmaxf(mx, __shfl_xor(mx, d));
    float pr[4]; float ssum = 0.f;
#pragma unroll
    for (int m = 0; m < 4; ++m) {
      int t = lane + m * 64;
      pr[m] = (t < NKV) ? expf(sc[m] - mx) : 0.0f;
      ssum += pr[m];
    }
#pragma unroll
    for (int d = 1; d < 64; d <<= 1) ssum += __shfl_xor(ssum, d);
    float acc[16];
#pragma unroll
    for (int d = 0; d < 16; ++d) acc[d] = 0.f;
#pragma unroll
    for (int m = 0; m < 4; ++m) {
      int t = lane + m * 64;
      if (t < NKV) {
        float p = pr[m];
#pragma unroll
        for (int d = 0; d < 16; ++d) acc[d] += p * kvls[t][32 + h * 16 + d];
      }
    }
#pragma unroll
    for (int d = 0; d < 16; ++d) {
#pragma unroll
      for (int s = 1; s < 64; s <<= 1) acc[d] += __shfl_xor(acc[d], s);
    }
    if (lane == 0) {
      float inv = 1.0f / ssum;
#pragma unroll
      for (int d = 0; d < 16; ++d) attno[qi][h * 16 + d] = acc[d] * inv;
    }
  }
  __syncthreads();

  if (tid < 128) {
    int n = tid >> 5, u = tid & 31;
    float acc = proj_b[u];
#pragma unroll
    for (int c = 0; c < 32; ++c) acc += attno[n][c] * proj_w[c * 32 + u];
    o_out[((size_t)b * 32 + u) * 4 + n] = acc;
  }
}

// ---------------------------------------------------------------------------
// Kernel C (v3, fill-shaped): 65536 blocks x 256 thr, 2 rows per block, one
// float4 store per thread, no loops.
// ---------------------------------------------------------------------------
__global__ __launch_bounds__(256) void upsample_kernel(const float* __restrict__ o_in,
                                                       float* __restrict__ out) {
  const int b = blockIdx.x;
  const int plane = b >> 8, rp = b & 255;
  const int t = threadIdx.x;
  const int r = rp * 2 + (t >> 7);
  const int c4 = (t & 127) * 4;
  const float4 o = *(const float4*)(o_in + (size_t)plane * 4);
  float wh = ((float)r + 0.5f) * (1.0f / 256.0f) - 0.5f;
  wh = fminf(fmaxf(wh, 0.0f), 1.0f);
  float4 v;
  float* vv = &v.x;
#pragma unroll
  for (int k = 0; k < 4; ++k) {
    float ww = ((float)(c4 + k) + 0.5f) * (1.0f / 256.0f) - 0.5f;
    ww = fminf(fmaxf(ww, 0.0f), 1.0f);
    float top = o.x + ww * (o.y - o.x);
    float bot = o.z + ww * (o.w - o.z);
    vv[k] = top + wh * (bot - top);
  }
  *(float4*)(out + (size_t)plane * (512 * 512) + (size_t)r * 512 + c4) = v;
}

extern "C" void kernel_launch(void* const* d_in, const int* in_sizes, int n_in,
                              void* d_out, int out_size, void* d_ws, size_t ws_size,
                              hipStream_t stream) {
  const float* x       = (const float*)d_in[0];
  const float* q_w     = (const float*)d_in[1];
  const float* q_b     = (const float*)d_in[2];
  const float* kv_w    = (const float*)d_in[3];
  const float* kv_b    = (const float*)d_in[4];
  const float* proj_w  = (const float*)d_in[5];
  const float* proj_b  = (const float*)d_in[6];
  const float* norm_g  = (const float*)d_in[7];
  const float* norm_b  = (const float*)d_in[8];
  const float* dconv_w = (const float*)d_in[9];
  const float* dconv_b = (const float*)d_in[10];
  float* out = (float*)d_out;

  float* pooled = (float*)d_ws;                       // 256*241 floats
  float* o_ws   = pooled + (size_t)BB * CC * NTOK;    // 1024 floats
  float* G4     = o_ws + 1024;                        // 256*128*512 floats
  size_t need = ((size_t)BB * CC * NTOK + 1024 + (size_t)256 * 128 * 512) * 4;

  if (ws_size >= need) {
    g4_kernel<<<16384, 256, 0, stream>>>(x, G4);
    win_kernel<<<1280, 512, 0, stream>>>(x, G4, pooled);
  } else {
    pool_fb<<<BB * CC * 2, 512, 0, stream>>>(x, pooled);
  }
  attn_kernel<<<BB, 512, 0, stream>>>(pooled, q_w, q_b, kv_w, kv_b, proj_w,
                                      proj_b, norm_g, norm_b, dconv_w, dconv_b,
                                      o_ws);
  upsample_kernel<<<65536, 256, 0, stream>>>(o_ws, out);
}

// Round 9
// 205.196 us; speedup vs baseline: 1.4711x; 1.0572x over previous
//
#include <hip/hip_runtime.h>
#include <math.h>

#define BB 8
#define CC 32
#define NTOK 241   // 4(q 2x2) + 121 + 64 + 36 + 16
#define NKV 237

// non-temporal float4 (bypass L2/L3 allocation for stream-once data)
typedef float f4v __attribute__((ext_vector_type(4)));
__device__ __forceinline__ float4 ntload4(const float* p) {
  f4v v = __builtin_nontemporal_load((const f4v*)p);
  return make_float4(v.x, v.y, v.z, v.w);
}
__device__ __forceinline__ void ntstore4(float* p, float4 v) {
  f4v t = {v.x, v.y, v.z, v.w};
  __builtin_nontemporal_store(t, (f4v*)p);
}

// ---------------------------------------------------------------------------
// Pool stage A: 256 planes x 64 bands(8 rows) = 16384 blocks, 256 thr.
// Thread sums 4 rows of one col-quad via NON-TEMPORAL loads (x is read-once;
// don't thrash L3) -> one float4 store into G4 [plane][128][512] (normal
// store: G4 is re-read by win_kernel, let it live in L2/L3).
// ---------------------------------------------------------------------------
__global__ __launch_bounds__(256) void g4_kernel(const float* __restrict__ x,
                                                 float* __restrict__ G4) {
  const int b = blockIdx.x;
  const int plane = b >> 6, band = b & 63;
  const int t = threadIdx.x;
  const int gh = t >> 7;                     // which 4-row group of the band
  const int c4 = (t & 127) * 4;
  const float* xp = x + (size_t)plane * (512 * 512) + (size_t)(band * 8 + gh * 4) * 512 + c4;
  float4 a0 = ntload4(xp);
  float4 a1 = ntload4(xp + 512);
  float4 a2 = ntload4(xp + 1024);
  float4 a3 = ntload4(xp + 1536);
  float4 s;
  s.x = (a0.x + a1.x) + (a2.x + a3.x);
  s.y = (a0.y + a1.y) + (a2.y + a3.y);
  s.z = (a0.z + a1.z) + (a2.z + a3.z);
  s.w = (a0.w + a1.w) + (a2.w + a3.w);
  *(float4*)(G4 + ((size_t)plane * 128 + band * 2 + gh) * 512 + c4) = s;
}

// ---------------------------------------------------------------------------
// Pool stage B: 256 planes x 5 levels = 1280 blocks, 512 thr. Assemble each
// H-window from G4 group sums + raw x edge rows (p11/p6 only), W-pool in LDS
// -> tokens. No atomics, each token written exactly once. (unchanged)
// ---------------------------------------------------------------------------
__global__ __launch_bounds__(512) void win_kernel(const float* __restrict__ x,
                                                  const float* __restrict__ G4,
                                                  float* __restrict__ pooled) {
  __shared__ float Y[11][520];               // 22.9 KB
  const int b = blockIdx.x;
  const int plane = b / 5, lvl = b - plane * 5;
  const int Ps[5]  = {2, 11, 8, 6, 4};
  const int KBs[5] = {0, 4, 125, 189, 225};
  const int p = Ps[lvl], kb = KBs[lvl];
  const int col = threadIdx.x;
  const float* xp = x + (size_t)plane * (512 * 512);
  const float* g4 = G4 + (size_t)plane * 128 * 512;

  for (int i = 0; i < p; ++i) {
    int s = (i * 512) / p, e = ((i + 1) * 512 + p - 1) / p;
    int gs = (s + 3) >> 2, ge = e >> 2;
    float sum = 0.f;
    for (int r = s; r < gs * 4; ++r) sum += xp[(size_t)r * 512 + col];
    float s0 = 0.f, s1 = 0.f;
    int g = gs;
    for (; g + 2 <= ge; g += 2) {
      s0 += g4[(size_t)g * 512 + col];
      s1 += g4[(size_t)(g + 1) * 512 + col];
    }
    if (g < ge) s0 += g4[(size_t)g * 512 + col];
    sum += s0 + s1;
    for (int r = ge * 4; r < e; ++r) sum += xp[(size_t)r * 512 + col];
    Y[i][col] = sum;
  }
  __syncthreads();

  if (col < p * p) {
    int i = col / p, j = col - i * p;
    int s = (i * 512) / p, e = ((i + 1) * 512 + p - 1) / p;
    int sw = (j * 512) / p, ew = ((j + 1) * 512 + p - 1) / p;
    float t0 = 0.f, t1 = 0.f;
    int c = sw;
    for (; c + 2 <= ew; c += 2) { t0 += Y[i][c]; t1 += Y[i][c + 1]; }
    if (c < ew) t0 += Y[i][c];
    pooled[(size_t)plane * NTOK + kb + i * p + j] =
        (t0 + t1) / (float)((e - s) * (ew - sw));
  }
}

// ---------------------------------------------------------------------------
// Fallback pool (validated R5 band kernel) if ws_size can't hold G4.
// ---------------------------------------------------------------------------
struct Win { int idx, s, e, left; float acc; };

template <int P, int SBASE>
__device__ __forceinline__ void wstep(Win& w, int nown, float v, int r,
                                      float* __restrict__ Y, int c) {
  if (w.left > 0) {
    w.acc += (r >= w.s) ? v : 0.0f;
    if (r == w.e - 1) {
      Y[(SBASE + (nown - w.left)) * 516 + c] = w.acc;
      w.left--; w.idx++;
      int sn = (w.idx * 512) / P;
      w.acc = (sn <= r) ? v : 0.0f;
      w.s = sn;
      w.e = ((w.idx + 1) * 512 + P - 1) / P;
    }
  }
}

template <int P>
__device__ __forceinline__ void winit(Win& w, int i0, int n) {
  w.idx = i0;
  w.s = (i0 * 512) / P;
  w.e = ((i0 + 1) * 512 + P - 1) / P;
  w.left = n;
  w.acc = 0.0f;
}

__global__ __launch_bounds__(512) void pool_fb(const float* __restrict__ x,
                                               float* __restrict__ pooled) {
  __shared__ float sh[8 * 512];
  __shared__ float Ybuf[16 * 516];
  const int plane = blockIdx.x >> 1;
  const int q = blockIdx.x & 1;
  const int tid = threadIdx.x;
  const int c = tid;
  const int lo = q ? 256 : 0;
  const int nb = q ? 32 : 35;
  int i0_2, n_2, i0_11, n_11, i0_8, n_8, i0_6, n_6, i0_4, n_4;
  if (q == 0) { i0_2 = 0; n_2 = 1; i0_11 = 0; n_11 = 6; i0_8 = 0; n_8 = 4; i0_6 = 0; n_6 = 3; i0_4 = 0; n_4 = 2; }
  else        { i0_2 = 1; n_2 = 1; i0_11 = 6; n_11 = 5; i0_8 = 4; n_8 = 4; i0_6 = 3; n_6 = 3; i0_4 = 2; n_4 = 2; }
  Win W2, W11, W8, W6, W4;
  winit<2>(W2, i0_2, n_2); winit<11>(W11, i0_11, n_11); winit<8>(W8, i0_8, n_8);
  winit<6>(W6, i0_6, n_6); winit<4>(W4, i0_4, n_4);
  const float* xp = x + (size_t)plane * (512 * 512);
  const int row0 = tid >> 7;
  const int cg = (tid & 127) * 4;
  float4 r0 = *(const float4*)(xp + (size_t)(lo + row0) * 512 + cg);
  float4 r1 = *(const float4*)(xp + (size_t)(lo + row0 + 4) * 512 + cg);
  for (int band = 0; band < nb; ++band) {
    *(float4*)(sh + row0 * 512 + cg) = r0;
    *(float4*)(sh + (row0 + 4) * 512 + cg) = r1;
    __syncthreads();
    if (band + 1 < nb) {
      int rb = lo + (band + 1) * 8;
      r0 = *(const float4*)(xp + (size_t)(rb + row0) * 512 + cg);
      r1 = *(const float4*)(xp + (size_t)(rb + row0 + 4) * 512 + cg);
    }
#pragma unroll
    for (int rr = 0; rr < 8; ++rr) {
      float v = sh[rr * 512 + c];
      int r = lo + band * 8 + rr;
      wstep<2, 0>(W2, n_2, v, r, Ybuf, c);
      wstep<11, 1>(W11, n_11, v, r, Ybuf, c);
      wstep<8, 7>(W8, n_8, v, r, Ybuf, c);
      wstep<6, 11>(W6, n_6, v, r, Ybuf, c);
      wstep<4, 14>(W4, n_4, v, r, Ybuf, c);
    }
    __syncthreads();
  }
  const int Ps[5]  = {2, 11, 8, 6, 4};
  const int KBs[5] = {0, 4, 125, 189, 225};
  const int SBs[5] = {0, 1, 7, 11, 14};
  const int i0s[5] = {i0_2, i0_11, i0_8, i0_6, i0_4};
  const int ns[5]  = {n_2, n_11, n_8, n_6, n_4};
  int cum[6]; cum[0] = 0;
#pragma unroll
  for (int l = 0; l < 5; ++l) cum[l + 1] = cum[l] + ns[l] * Ps[l];
  if (tid < cum[5]) {
    int l = 0;
    while (tid >= cum[l + 1]) ++l;
    int P = Ps[l];
    int rel = tid - cum[l];
    int li = rel / P, j = rel - li * P;
    int i = i0s[l] + li;
    int s = (i * 512) / P, e = ((i + 1) * 512 + P - 1) / P;
    int sw = (j * 512) / P, ew = ((j + 1) * 512 + P - 1) / P;
    const float* row = &Ybuf[(SBs[l] + li) * 516];
    float t0 = 0.f, t1 = 0.f, t2 = 0.f, t3 = 0.f;
    int cc = sw;
    for (; cc + 4 <= ew; cc += 4) {
      t0 += row[cc]; t1 += row[cc + 1]; t2 += row[cc + 2]; t3 += row[cc + 3];
    }
    for (; cc < ew; ++cc) t0 += row[cc];
    float val = ((t0 + t1) + (t2 + t3)) / (float)((e - s) * (ew - sw));
    pooled[(size_t)plane * NTOK + KBs[l] + i * P + j] = val;
  }
}

// ---------------------------------------------------------------------------
// Kernel B: token pipeline (unchanged, validated).
// ---------------------------------------------------------------------------
__global__ __launch_bounds__(512) void attn_kernel(
    const float* __restrict__ pooled,
    const float* __restrict__ q_w, const float* __restrict__ q_b,
    const float* __restrict__ kv_w, const float* __restrict__ kv_b,
    const float* __restrict__ proj_w, const float* __restrict__ proj_b,
    const float* __restrict__ norm_g, const float* __restrict__ norm_b,
    const float* __restrict__ dconv_w, const float* __restrict__ dconv_b,
    float* __restrict__ o_out) {
  __shared__ float pl[CC * NTOK];
  __shared__ float toks[NKV][33];
  __shared__ float kvls[NKV][65];      // k: 0..31, v: 32..63
  __shared__ float kvw[CC * 64];
  __shared__ float dw[4 * CC * 9];
  __shared__ float dbias[4 * CC];
  __shared__ float qbias[CC], kvb[64], gln[CC], bln[CC];
  __shared__ float qtok[4][CC];
  __shared__ float attno[4][33];

  const int b = blockIdx.x, tid = threadIdx.x;
  const float* plg = pooled + (size_t)b * CC * NTOK;
  for (int i = tid; i < CC * NTOK; i += 512) pl[i] = plg[i];
  for (int i = tid; i < CC * 64; i += 512) kvw[i] = kv_w[i];
  for (int i = tid; i < 4 * CC * 9; i += 512) dw[i] = dconv_w[i];
  if (tid < 4 * CC) dbias[tid] = dconv_b[tid];
  if (tid < CC) { qbias[tid] = q_b[tid]; gln[tid] = norm_g[tid]; bln[tid] = norm_b[tid]; }
  if (tid >= 64 && tid < 128) kvb[tid - 64] = kv_b[tid - 64];
  __syncthreads();

  for (int item = tid; item < NKV * CC; item += 512) {
    int t = item >> 5, c = item & 31;
    int l, p, kb_, tb;
    if (t < 121)      { l = 0; p = 11; kb_ = 4;   tb = 0; }
    else if (t < 185) { l = 1; p = 8;  kb_ = 125; tb = 121; }
    else if (t < 221) { l = 2; p = 6;  kb_ = 189; tb = 185; }
    else              { l = 3; p = 4;  kb_ = 225; tb = 221; }
    int ti = t - tb;
    int i = ti / p, j = ti - i * p;
    const float* plc = pl + c * NTOK + kb_;
    const float* w9 = dw + (l * CC + c) * 9;
    float acc = dbias[l * CC + c];
#pragma unroll
    for (int dy = -1; dy <= 1; ++dy)
#pragma unroll
      for (int dx = -1; dx <= 1; ++dx) {
        int ii = i + dy, jj = j + dx;
        if (ii >= 0 && ii < p && jj >= 0 && jj < p)
          acc += w9[(dy + 1) * 3 + (dx + 1)] * plc[ii * p + jj];
      }
    toks[t][c] = plc[i * p + j] + acc;
  }
  __syncthreads();

  if (tid < NKV) {
    float xv[32]; float m = 0.f;
#pragma unroll
    for (int c = 0; c < 32; ++c) { xv[c] = toks[tid][c]; m += xv[c]; }
    m *= (1.0f / 32.0f);
    float v = 0.f;
#pragma unroll
    for (int c = 0; c < 32; ++c) { float d = xv[c] - m; v += d * d; }
    v *= (1.0f / 32.0f);
    float rs = rsqrtf(v + 1e-5f);
#pragma unroll
    for (int c = 0; c < 32; ++c) toks[tid][c] = (xv[c] - m) * rs * gln[c] + bln[c];
  } else if (tid >= 384) {
    int it = tid - 384;
    int n = it >> 5, u = it & 31;
    float acc = qbias[u];
#pragma unroll
    for (int c = 0; c < 32; ++c) acc += pl[c * NTOK + n] * q_w[c * 32 + u];
    qtok[n][u] = acc * 0.25f;         // fold scale = hd^-0.5
  }
  __syncthreads();

  for (int item = tid; item < NKV * 64; item += 512) {
    int t = item >> 6, u = item & 63;
    float acc = kvb[u];
#pragma unroll
    for (int c = 0; c < 32; ++c) acc += toks[t][c] * kvw[c * 64 + u];
    kvls[t][u] = acc;
  }
  __syncthreads();

  {
    int wave = tid >> 6, lane = tid & 63;
    int h = wave >> 2, qi = wave & 3;
    float qv[16];
#pragma unroll
    for (int d = 0; d < 16; ++d) qv[d] = qtok[qi][h * 16 + d];
    float sc[4];
#pragma unroll
    for (int m = 0; m < 4; ++m) {
      int t = lane + m * 64;
      float s = -1e30f;
      if (t < NKV) {
        s = 0.f;
#pragma unroll
        for (int d = 0; d < 16; ++d) s += qv[d] * kvls[t][h * 16 + d];
      }
      sc[m] = s;
    }
    float mx = fmaxf(fmaxf(sc[0], sc[1]), fmaxf(sc[2], sc[3]));
#pragma unroll
    for (int d = 1; d < 64; d <<= 1) mx = fmaxf(mx, __shfl_xor(mx, d));
    float pr[4]; float ssum = 0.f;
#pragma unroll
    for (int m = 0; m < 4; ++m) {
      int t = lane + m * 64;
      pr[m] = (t < NKV) ? expf(sc[m] - mx) : 0.0f;
      ssum += pr[m];
    }
#pragma unroll
    for (int d = 1; d < 64; d <<= 1) ssum += __shfl_xor(ssum, d);
    float acc[16];
#pragma unroll
    for (int d = 0; d < 16; ++d) acc[d] = 0.f;
#pragma unroll
    for (int m = 0; m < 4; ++m) {
      int t = lane + m * 64;
      if (t < NKV) {
        float p = pr[m];
#pragma unroll
        for (int d = 0; d < 16; ++d) acc[d] += p * kvls[t][32 + h * 16 + d];
      }
    }
#pragma unroll
    for (int d = 0; d < 16; ++d) {
#pragma unroll
      for (int s = 1; s < 64; s <<= 1) acc[d] += __shfl_xor(acc[d], s);
    }
    if (lane == 0) {
      float inv = 1.0f / ssum;
#pragma unroll
      for (int d = 0; d < 16; ++d) attno[qi][h * 16 + d] = acc[d] * inv;
    }
  }
  __syncthreads();

  if (tid < 128) {
    int n = tid >> 5, u = tid & 31;
    float acc = proj_b[u];
#pragma unroll
    for (int c = 0; c < 32; ++c) acc += attno[n][c] * proj_w[c * 32 + u];
    o_out[((size_t)b * 32 + u) * 4 + n] = acc;
  }
}

// ---------------------------------------------------------------------------
// Kernel C (v4): bilinear upsample with NON-TEMPORAL stores (out is
// write-once; don't thrash L3). 256 planes x 32 chunks = 8192 blocks,
// 256 thr; thread does 8 NT float4 stores (16 rows/block).
// ---------------------------------------------------------------------------
__global__ __launch_bounds__(256) void upsample_kernel(const float* __restrict__ o_in,
                                                       float* __restrict__ out) {
  const int b = blockIdx.x;
  const int plane = b >> 5, chunk = b & 31;
  const int t = threadIdx.x;
  const int sub = t >> 7, col4 = (t & 127) * 4;
  const float4 o = *(const float4*)(o_in + (size_t)plane * 4);

  float top[4], bot[4];
#pragma unroll
  for (int k = 0; k < 4; ++k) {
    float ww = ((float)(col4 + k) + 0.5f) * (1.0f / 256.0f) - 0.5f;
    ww = fminf(fmaxf(ww, 0.0f), 1.0f);
    top[k] = o.x + ww * (o.y - o.x);
    bot[k] = o.z + ww * (o.w - o.z);
  }
  float* outp = out + (size_t)plane * (512 * 512);
#pragma unroll
  for (int i = 0; i < 8; ++i) {
    int r = chunk * 16 + 2 * i + sub;
    float wh = ((float)r + 0.5f) * (1.0f / 256.0f) - 0.5f;
    wh = fminf(fmaxf(wh, 0.0f), 1.0f);
    float4 v;
    v.x = top[0] + wh * (bot[0] - top[0]);
    v.y = top[1] + wh * (bot[1] - top[1]);
    v.z = top[2] + wh * (bot[2] - top[2]);
    v.w = top[3] + wh * (bot[3] - top[3]);
    ntstore4(outp + (size_t)r * 512 + col4, v);
  }
}

extern "C" void kernel_launch(void* const* d_in, const int* in_sizes, int n_in,
                              void* d_out, int out_size, void* d_ws, size_t ws_size,
                              hipStream_t stream) {
  const float* x       = (const float*)d_in[0];
  const float* q_w     = (const float*)d_in[1];
  const float* q_b     = (const float*)d_in[2];
  const float* kv_w    = (const float*)d_in[3];
  const float* kv_b    = (const float*)d_in[4];
  const float* proj_w  = (const float*)d_in[5];
  const float* proj_b  = (const float*)d_in[6];
  const float* norm_g  = (const float*)d_in[7];
  const float* norm_b  = (const float*)d_in[8];
  const float* dconv_w = (const float*)d_in[9];
  const float* dconv_b = (const float*)d_in[10];
  float* out = (float*)d_out;

  float* pooled = (float*)d_ws;                       // 256*241 floats
  float* o_ws   = pooled + (size_t)BB * CC * NTOK;    // 1024 floats
  float* G4     = o_ws + 1024;                        // 256*128*512 floats
  size_t need = ((size_t)BB * CC * NTOK + 1024 + (size_t)256 * 128 * 512) * 4;

  if (ws_size >= need) {
    g4_kernel<<<16384, 256, 0, stream>>>(x, G4);
    win_kernel<<<1280, 512, 0, stream>>>(x, G4, pooled);
  } else {
    pool_fb<<<BB * CC * 2, 512, 0, stream>>>(x, pooled);
  }
  attn_kernel<<<BB, 512, 0, stream>>>(pooled, q_w, q_b, kv_w, kv_b, proj_w,
                                      proj_b, norm_g, norm_b, dconv_w, dconv_b,
                                      o_ws);
  upsample_kernel<<<8192, 256, 0, stream>>>(o_ws, out);
}

// Round 10
// 201.863 us; speedup vs baseline: 1.4954x; 1.0165x over previous
//
#include <hip/hip_runtime.h>
#include <math.h>

#define BB 8
#define CC 32
#define NTOK 241   // 4(q 2x2) + 121 + 64 + 36 + 16
#define NKV 237

// non-temporal float4 store (bypass cache allocation for write-once stream)
typedef float f4v __attribute__((ext_vector_type(4)));
__device__ __forceinline__ void ntstore4(float* p, float4 v) {
  f4v t = {v.x, v.y, v.z, v.w};
  __builtin_nontemporal_store(t, (f4v*)p);
}

// ---------------------------------------------------------------------------
// Pool stage A: 256 planes x 64 bands(8 rows) = 16384 blocks, 256 thr.
// TEMPORAL loads of x (x = 256 MB = L3 size; read-allocate makes x L3-resident
// across graph replays -> lower latency -> higher read BW under the per-CU
// outstanding-miss cap). G4 stores temporal (re-read by win_kernel).
// ---------------------------------------------------------------------------
__global__ __launch_bounds__(256) void g4_kernel(const float* __restrict__ x,
                                                 float* __restrict__ G4) {
  const int b = blockIdx.x;
  const int plane = b >> 6, band = b & 63;
  const int t = threadIdx.x;
  const int gh = t >> 7;                     // which 4-row group of the band
  const int c4 = (t & 127) * 4;
  const float* xp = x + (size_t)plane * (512 * 512) + (size_t)(band * 8 + gh * 4) * 512 + c4;
  float4 a0 = *(const float4*)(xp);
  float4 a1 = *(const float4*)(xp + 512);
  float4 a2 = *(const float4*)(xp + 1024);
  float4 a3 = *(const float4*)(xp + 1536);
  float4 s;
  s.x = (a0.x + a1.x) + (a2.x + a3.x);
  s.y = (a0.y + a1.y) + (a2.y + a3.y);
  s.z = (a0.z + a1.z) + (a2.z + a3.z);
  s.w = (a0.w + a1.w) + (a2.w + a3.w);
  *(float4*)(G4 + ((size_t)plane * 128 + band * 2 + gh) * 512 + c4) = s;
}

// ---------------------------------------------------------------------------
// Pool stage B: 256 planes x 5 levels = 1280 blocks, 512 thr. Assemble each
// H-window from G4 group sums + raw x edge rows (p11/p6 only), W-pool in LDS
// -> tokens. No atomics, each token written exactly once. (unchanged)
// ---------------------------------------------------------------------------
__global__ __launch_bounds__(512) void win_kernel(const float* __restrict__ x,
                                                  const float* __restrict__ G4,
                                                  float* __restrict__ pooled) {
  __shared__ float Y[11][520];               // 22.9 KB
  const int b = blockIdx.x;
  const int plane = b / 5, lvl = b - plane * 5;
  const int Ps[5]  = {2, 11, 8, 6, 4};
  const int KBs[5] = {0, 4, 125, 189, 225};
  const int p = Ps[lvl], kb = KBs[lvl];
  const int col = threadIdx.x;
  const float* xp = x + (size_t)plane * (512 * 512);
  const float* g4 = G4 + (size_t)plane * 128 * 512;

  for (int i = 0; i < p; ++i) {
    int s = (i * 512) / p, e = ((i + 1) * 512 + p - 1) / p;
    int gs = (s + 3) >> 2, ge = e >> 2;
    float sum = 0.f;
    for (int r = s; r < gs * 4; ++r) sum += xp[(size_t)r * 512 + col];
    float s0 = 0.f, s1 = 0.f;
    int g = gs;
    for (; g + 2 <= ge; g += 2) {
      s0 += g4[(size_t)g * 512 + col];
      s1 += g4[(size_t)(g + 1) * 512 + col];
    }
    if (g < ge) s0 += g4[(size_t)g * 512 + col];
    sum += s0 + s1;
    for (int r = ge * 4; r < e; ++r) sum += xp[(size_t)r * 512 + col];
    Y[i][col] = sum;
  }
  __syncthreads();

  if (col < p * p) {
    int i = col / p, j = col - i * p;
    int s = (i * 512) / p, e = ((i + 1) * 512 + p - 1) / p;
    int sw = (j * 512) / p, ew = ((j + 1) * 512 + p - 1) / p;
    float t0 = 0.f, t1 = 0.f;
    int c = sw;
    for (; c + 2 <= ew; c += 2) { t0 += Y[i][c]; t1 += Y[i][c + 1]; }
    if (c < ew) t0 += Y[i][c];
    pooled[(size_t)plane * NTOK + kb + i * p + j] =
        (t0 + t1) / (float)((e - s) * (ew - sw));
  }
}

// ---------------------------------------------------------------------------
// Fallback pool (validated R5 band kernel) if ws_size can't hold G4.
// ---------------------------------------------------------------------------
struct Win { int idx, s, e, left; float acc; };

template <int P, int SBASE>
__device__ __forceinline__ void wstep(Win& w, int nown, float v, int r,
                                      float* __restrict__ Y, int c) {
  if (w.left > 0) {
    w.acc += (r >= w.s) ? v : 0.0f;
    if (r == w.e - 1) {
      Y[(SBASE + (nown - w.left)) * 516 + c] = w.acc;
      w.left--; w.idx++;
      int sn = (w.idx * 512) / P;
      w.acc = (sn <= r) ? v : 0.0f;
      w.s = sn;
      w.e = ((w.idx + 1) * 512 + P - 1) / P;
    }
  }
}

template <int P>
__device__ __forceinline__ void winit(Win& w, int i0, int n) {
  w.idx = i0;
  w.s = (i0 * 512) / P;
  w.e = ((i0 + 1) * 512 + P - 1) / P;
  w.left = n;
  w.acc = 0.0f;
}

__global__ __launch_bounds__(512) void pool_fb(const float* __restrict__ x,
                                               float* __restrict__ pooled) {
  __shared__ float sh[8 * 512];
  __shared__ float Ybuf[16 * 516];
  const int plane = blockIdx.x >> 1;
  const int q = blockIdx.x & 1;
  const int tid = threadIdx.x;
  const int c = tid;
  const int lo = q ? 256 : 0;
  const int nb = q ? 32 : 35;
  int i0_2, n_2, i0_11, n_11, i0_8, n_8, i0_6, n_6, i0_4, n_4;
  if (q == 0) { i0_2 = 0; n_2 = 1; i0_11 = 0; n_11 = 6; i0_8 = 0; n_8 = 4; i0_6 = 0; n_6 = 3; i0_4 = 0; n_4 = 2; }
  else        { i0_2 = 1; n_2 = 1; i0_11 = 6; n_11 = 5; i0_8 = 4; n_8 = 4; i0_6 = 3; n_6 = 3; i0_4 = 2; n_4 = 2; }
  Win W2, W11, W8, W6, W4;
  winit<2>(W2, i0_2, n_2); winit<11>(W11, i0_11, n_11); winit<8>(W8, i0_8, n_8);
  winit<6>(W6, i0_6, n_6); winit<4>(W4, i0_4, n_4);
  const float* xp = x + (size_t)plane * (512 * 512);
  const int row0 = tid >> 7;
  const int cg = (tid & 127) * 4;
  float4 r0 = *(const float4*)(xp + (size_t)(lo + row0) * 512 + cg);
  float4 r1 = *(const float4*)(xp + (size_t)(lo + row0 + 4) * 512 + cg);
  for (int band = 0; band < nb; ++band) {
    *(float4*)(sh + row0 * 512 + cg) = r0;
    *(float4*)(sh + (row0 + 4) * 512 + cg) = r1;
    __syncthreads();
    if (band + 1 < nb) {
      int rb = lo + (band + 1) * 8;
      r0 = *(const float4*)(xp + (size_t)(rb + row0) * 512 + cg);
      r1 = *(const float4*)(xp + (size_t)(rb + row0 + 4) * 512 + cg);
    }
#pragma unroll
    for (int rr = 0; rr < 8; ++rr) {
      float v = sh[rr * 512 + c];
      int r = lo + band * 8 + rr;
      wstep<2, 0>(W2, n_2, v, r, Ybuf, c);
      wstep<11, 1>(W11, n_11, v, r, Ybuf, c);
      wstep<8, 7>(W8, n_8, v, r, Ybuf, c);
      wstep<6, 11>(W6, n_6, v, r, Ybuf, c);
      wstep<4, 14>(W4, n_4, v, r, Ybuf, c);
    }
    __syncthreads();
  }
  const int Ps[5]  = {2, 11, 8, 6, 4};
  const int KBs[5] = {0, 4, 125, 189, 225};
  const int SBs[5] = {0, 1, 7, 11, 14};
  const int i0s[5] = {i0_2, i0_11, i0_8, i0_6, i0_4};
  const int ns[5]  = {n_2, n_11, n_8, n_6, n_4};
  int cum[6]; cum[0] = 0;
#pragma unroll
  for (int l = 0; l < 5; ++l) cum[l + 1] = cum[l] + ns[l] * Ps[l];
  if (tid < cum[5]) {
    int l = 0;
    while (tid >= cum[l + 1]) ++l;
    int P = Ps[l];
    int rel = tid - cum[l];
    int li = rel / P, j = rel - li * P;
    int i = i0s[l] + li;
    int s = (i * 512) / P, e = ((i + 1) * 512 + P - 1) / P;
    int sw = (j * 512) / P, ew = ((j + 1) * 512 + P - 1) / P;
    const float* row = &Ybuf[(SBs[l] + li) * 516];
    float t0 = 0.f, t1 = 0.f, t2 = 0.f, t3 = 0.f;
    int cc = sw;
    for (; cc + 4 <= ew; cc += 4) {
      t0 += row[cc]; t1 += row[cc + 1]; t2 += row[cc + 2]; t3 += row[cc + 3];
    }
    for (; cc < ew; ++cc) t0 += row[cc];
    float val = ((t0 + t1) + (t2 + t3)) / (float)((e - s) * (ew - sw));
    pooled[(size_t)plane * NTOK + KBs[l] + i * P + j] = val;
  }
}

// ---------------------------------------------------------------------------
// Kernel B: token pipeline (unchanged, validated).
// ---------------------------------------------------------------------------
__global__ __launch_bounds__(512) void attn_kernel(
    const float* __restrict__ pooled,
    const float* __restrict__ q_w, const float* __restrict__ q_b,
    const float* __restrict__ kv_w, const float* __restrict__ kv_b,
    const float* __restrict__ proj_w, const float* __restrict__ proj_b,
    const float* __restrict__ norm_g, const float* __restrict__ norm_b,
    const float* __restrict__ dconv_w, const float* __restrict__ dconv_b,
    float* __restrict__ o_out) {
  __shared__ float pl[CC * NTOK];
  __shared__ float toks[NKV][33];
  __shared__ float kvls[NKV][65];      // k: 0..31, v: 32..63
  __shared__ float kvw[CC * 64];
  __shared__ float dw[4 * CC * 9];
  __shared__ float dbias[4 * CC];
  __shared__ float qbias[CC], kvb[64], gln[CC], bln[CC];
  __shared__ float qtok[4][CC];
  __shared__ float attno[4][33];

  const int b = blockIdx.x, tid = threadIdx.x;
  const float* plg = pooled + (size_t)b * CC * NTOK;
  for (int i = tid; i < CC * NTOK; i += 512) pl[i] = plg[i];
  for (int i = tid; i < CC * 64; i += 512) kvw[i] = kv_w[i];
  for (int i = tid; i < 4 * CC * 9; i += 512) dw[i] = dconv_w[i];
  if (tid < 4 * CC) dbias[tid] = dconv_b[tid];
  if (tid < CC) { qbias[tid] = q_b[tid]; gln[tid] = norm_g[tid]; bln[tid] = norm_b[tid]; }
  if (tid >= 64 && tid < 128) kvb[tid - 64] = kv_b[tid - 64];
  __syncthreads();

  for (int item = tid; item < NKV * CC; item += 512) {
    int t = item >> 5, c = item & 31;
    int l, p, kb_, tb;
    if (t < 121)      { l = 0; p = 11; kb_ = 4;   tb = 0; }
    else if (t < 185) { l = 1; p = 8;  kb_ = 125; tb = 121; }
    else if (t < 221) { l = 2; p = 6;  kb_ = 189; tb = 185; }
    else              { l = 3; p = 4;  kb_ = 225; tb = 221; }
    int ti = t - tb;
    int i = ti / p, j = ti - i * p;
    const float* plc = pl + c * NTOK + kb_;
    const float* w9 = dw + (l * CC + c) * 9;
    float acc = dbias[l * CC + c];
#pragma unroll
    for (int dy = -1; dy <= 1; ++dy)
#pragma unroll
      for (int dx = -1; dx <= 1; ++dx) {
        int ii = i + dy, jj = j + dx;
        if (ii >= 0 && ii < p && jj >= 0 && jj < p)
          acc += w9[(dy + 1) * 3 + (dx + 1)] * plc[ii * p + jj];
      }
    toks[t][c] = plc[i * p + j] + acc;
  }
  __syncthreads();

  if (tid < NKV) {
    float xv[32]; float m = 0.f;
#pragma unroll
    for (int c = 0; c < 32; ++c) { xv[c] = toks[tid][c]; m += xv[c]; }
    m *= (1.0f / 32.0f);
    float v = 0.f;
#pragma unroll
    for (int c = 0; c < 32; ++c) { float d = xv[c] - m; v += d * d; }
    v *= (1.0f / 32.0f);
    float rs = rsqrtf(v + 1e-5f);
#pragma unroll
    for (int c = 0; c < 32; ++c) toks[tid][c] = (xv[c] - m) * rs * gln[c] + bln[c];
  } else if (tid >= 384) {
    int it = tid - 384;
    int n = it >> 5, u = it & 31;
    float acc = qbias[u];
#pragma unroll
    for (int c = 0; c < 32; ++c) acc += pl[c * NTOK + n] * q_w[c * 32 + u];
    qtok[n][u] = acc * 0.25f;         // fold scale = hd^-0.5
  }
  __syncthreads();

  for (int item = tid; item < NKV * 64; item += 512) {
    int t = item >> 6, u = item & 63;
    float acc = kvb[u];
#pragma unroll
    for (int c = 0; c < 32; ++c) acc += toks[t][c] * kvw[c * 64 + u];
    kvls[t][u] = acc;
  }
  __syncthreads();

  {
    int wave = tid >> 6, lane = tid & 63;
    int h = wave >> 2, qi = wave & 3;
    float qv[16];
#pragma unroll
    for (int d = 0; d < 16; ++d) qv[d] = qtok[qi][h * 16 + d];
    float sc[4];
#pragma unroll
    for (int m = 0; m < 4; ++m) {
      int t = lane + m * 64;
      float s = -1e30f;
      if (t < NKV) {
        s = 0.f;
#pragma unroll
        for (int d = 0; d < 16; ++d) s += qv[d] * kvls[t][h * 16 + d];
      }
      sc[m] = s;
    }
    float mx = fmaxf(fmaxf(sc[0], sc[1]), fmaxf(sc[2], sc[3]));
#pragma unroll
    for (int d = 1; d < 64; d <<= 1) mx = fmaxf(mx, __shfl_xor(mx, d));
    float pr[4]; float ssum = 0.f;
#pragma unroll
    for (int m = 0; m < 4; ++m) {
      int t = lane + m * 64;
      pr[m] = (t < NKV) ? expf(sc[m] - mx) : 0.0f;
      ssum += pr[m];
    }
#pragma unroll
    for (int d = 1; d < 64; d <<= 1) ssum += __shfl_xor(ssum, d);
    float acc[16];
#pragma unroll
    for (int d = 0; d < 16; ++d) acc[d] = 0.f;
#pragma unroll
    for (int m = 0; m < 4; ++m) {
      int t = lane + m * 64;
      if (t < NKV) {
        float p = pr[m];
#pragma unroll
        for (int d = 0; d < 16; ++d) acc[d] += p * kvls[t][32 + h * 16 + d];
      }
    }
#pragma unroll
    for (int d = 0; d < 16; ++d) {
#pragma unroll
      for (int s = 1; s < 64; s <<= 1) acc[d] += __shfl_xor(acc[d], s);
    }
    if (lane == 0) {
      float inv = 1.0f / ssum;
#pragma unroll
      for (int d = 0; d < 16; ++d) attno[qi][h * 16 + d] = acc[d] * inv;
    }
  }
  __syncthreads();

  if (tid < 128) {
    int n = tid >> 5, u = tid & 31;
    float acc = proj_b[u];
#pragma unroll
    for (int c = 0; c < 32; ++c) acc += attno[n][c] * proj_w[c * 32 + u];
    o_out[((size_t)b * 32 + u) * 4 + n] = acc;
  }
}

// ---------------------------------------------------------------------------
// Kernel C (v5, fill-clone): 256 blocks = 1 plane each (1 MB monotonic
// contiguous extent per block, like rocclr fill's ~4.7MB/block shape),
// 256 thr, 2 rows (4 KB) per iteration, NT dwordx4 stores, unroll 4.
// ---------------------------------------------------------------------------
__global__ __launch_bounds__(256) void upsample_kernel(const float* __restrict__ o_in,
                                                       float* __restrict__ out) {
  const int plane = blockIdx.x;
  const int t = threadIdx.x;
  const int rsub = t >> 7;                   // 0..1
  const int col4 = (t & 127) * 4;
  const float4 o = *(const float4*)(o_in + (size_t)plane * 4);

  float top[4], bot[4];
#pragma unroll
  for (int k = 0; k < 4; ++k) {
    float ww = ((float)(col4 + k) + 0.5f) * (1.0f / 256.0f) - 0.5f;
    ww = fminf(fmaxf(ww, 0.0f), 1.0f);
    top[k] = o.x + ww * (o.y - o.x);
    bot[k] = o.z + ww * (o.w - o.z);
  }
  float* outp = out + (size_t)plane * (512 * 512);
#pragma unroll 4
  for (int i = 0; i < 256; ++i) {
    int r = 2 * i + rsub;
    float wh = ((float)r + 0.5f) * (1.0f / 256.0f) - 0.5f;
    wh = fminf(fmaxf(wh, 0.0f), 1.0f);
    float4 v;
    v.x = top[0] + wh * (bot[0] - top[0]);
    v.y = top[1] + wh * (bot[1] - top[1]);
    v.z = top[2] + wh * (bot[2] - top[2]);
    v.w = top[3] + wh * (bot[3] - top[3]);
    ntstore4(outp + (size_t)r * 512 + col4, v);
  }
}

extern "C" void kernel_launch(void* const* d_in, const int* in_sizes, int n_in,
                              void* d_out, int out_size, void* d_ws, size_t ws_size,
                              hipStream_t stream) {
  const float* x       = (const float*)d_in[0];
  const float* q_w     = (const float*)d_in[1];
  const float* q_b     = (const float*)d_in[2];
  const float* kv_w    = (const float*)d_in[3];
  const float* kv_b    = (const float*)d_in[4];
  const float* proj_w  = (const float*)d_in[5];
  const float* proj_b  = (const float*)d_in[6];
  const float* norm_g  = (const float*)d_in[7];
  const float* norm_b  = (const float*)d_in[8];
  const float* dconv_w = (const float*)d_in[9];
  const float* dconv_b = (const float*)d_in[10];
  float* out = (float*)d_out;

  float* pooled = (float*)d_ws;                       // 256*241 floats
  float* o_ws   = pooled + (size_t)BB * CC * NTOK;    // 1024 floats
  float* G4     = o_ws + 1024;                        // 256*128*512 floats
  size_t need = ((size_t)BB * CC * NTOK + 1024 + (size_t)256 * 128 * 512) * 4;

  if (ws_size >= need) {
    g4_kernel<<<16384, 256, 0, stream>>>(x, G4);
    win_kernel<<<1280, 512, 0, stream>>>(x, G4, pooled);
  } else {
    pool_fb<<<BB * CC * 2, 512, 0, stream>>>(x, pooled);
  }
  attn_kernel<<<BB, 512, 0, stream>>>(pooled, q_w, q_b, kv_w, kv_b, proj_w,
                                      proj_b, norm_g, norm_b, dconv_w, dconv_b,
                                      o_ws);
  upsample_kernel<<<256, 256, 0, stream>>>(o_ws, out);
}